// Round 4
// baseline (293.924 us; speedup 1.0000x reference)
//
#include <hip/hip_runtime.h>

// Attention_Critic on MI355X — round 13: kill barrier drains + re-grid stats.
//  - k_prep2: stats now 2048 blocks (8n x 256 chunks x 64 rows, 8-iter loops)
//    merged with weight-prep (60 blocks) in one 2108-block launch. Partials
//    laid out [n][c][160] so k_fin's fold is coalesced.
//  - k_fin: 8 blocks, 160 threads fold 256 chunks with consecutive-address loads.
//  - k_enc6 (= enc5 dataflow, barrier discipline changed): all __syncthreads ->
//    lgkmcnt(0)+s_barrier. Global stores no longer drained at barriers (nothing
//    in-kernel reads them); they drain at endpgm.
//  - k_attn / k_critic: same lgkm-only barriers. Logic unchanged.
//
// ws layout (bytes):
//   [0,256)          int flag (1 = bf16 inputs, 0 = f32)
//   [1024,+1310720)  stats partials f32 [8][256][160]  (chunk-major, 160=80f x {S,Q})
//   [1311744,+5120)  mst_g f32 [8][80][2]  (mean, rstd)
//   [1316864,...)    Wsa_t bf16 [8][128 col][104 k]
//   [1529856,...)    Wse_t bf16 [8][128 col][72 k]
//   [1677312,...)    Wp_t  bf16 [3 mat][128 col][136 k]  (mat 0=sel,1=key,2=val)
//   [1781760,...)    Wc1t  bf16 [8][128 col][256 k]
//   [2306048,+32M)   SE  bf16 [8][16384][128]
//   [+32M,+64M)      SEL bf16 [8][16384][128]  (attn output overwrites in place)
//   [+64M,+96M)      KEY bf16 [8][16384][128]
//   [+96M,+128M)     VAL bf16 [8][16384][128]

typedef unsigned short u16;
typedef unsigned int u32;

#define NA 8
#define BATCH 16384
#define SD 64
#define AD 16
#define IND 80
#define HID 128
#define HEADS 4
#define ATT 32
#define EPS 1e-5f
#define KP 136    // u16 stride, 128-k tiles
#define KP3 104   // u16 stride, 96-k tiles (Wsa_t)
#define KPS 72    // u16 stride, 64-k tiles (Wse_t)
#define VTS 68    // u16 stride, valt [32 d][64 row']
#define WBS 24    // u16 stride, softmax weight tiles

using short8 = __attribute__((ext_vector_type(8))) short;
using float4f = __attribute__((ext_vector_type(4))) float;
#define MFMA16(a, b, c) __builtin_amdgcn_mfma_f32_16x16x32_bf16((a), (b), (c), 0, 0, 0)

__device__ __forceinline__ float bf2f(u16 u) { union { u32 i; float f; } v; v.i = ((u32)u) << 16; return v.f; }
__device__ __forceinline__ float lo2f(u32 w) { union { u32 i; float f; } v; v.i = w << 16; return v.f; }
__device__ __forceinline__ float hi2f(u32 w) { union { u32 i; float f; } v; v.i = w & 0xffff0000u; return v.f; }
__device__ __forceinline__ u16 f2bf(float f) {
  union { float f; u32 i; } v; v.f = f;
  u32 x = v.i;
  x += 0x7fffu + ((x >> 16) & 1u);   // RNE
  return (u16)(x >> 16);
}
__device__ __forceinline__ float lrelu(float x) { return x > 0.f ? x : 0.01f * x; }
__device__ __forceinline__ float ldin(const void* p, size_t i, bool bf) {
  return bf ? bf2f(((const u16*)p)[i]) : ((const float*)p)[i];
}
__device__ __forceinline__ u16 ldbf(const void* p, size_t i, bool bf) {
  return bf ? ((const u16*)p)[i] : f2bf(((const float*)p)[i]);
}
__device__ __forceinline__ short8 lds_s8(const u16* p) {   // 16B LDS load, 4B-aligned ok
  union { short8 v; u32 u[4]; } t;
  const u32* q = (const u32*)p;
  t.u[0] = q[0]; t.u[1] = q[1]; t.u[2] = q[2]; t.u[3] = q[3];
  return t.v;
}
// Barrier that orders LDS only: global stores stay in flight (nothing in-kernel
// reads them). Compiler-generated ds_read/global_load keep their own waits.
__device__ __forceinline__ void barlg() {
  asm volatile("s_waitcnt lgkmcnt(0)" ::: "memory");
  __builtin_amdgcn_s_barrier();
}

// ---------------- K1: merged BN stats (2048 blocks) + weight prep (60 blocks) ----------------
// blocks [0,2048): stats chunk (n = blk>>8, c = blk&255, rows c*64..c*64+63);
// blocks [2048,2108): weight prep.
__global__ __launch_bounds__(256) void k_prep2(
    const void* __restrict__ s, const void* __restrict__ a,
    const void* __restrict__ Wsa, const void* __restrict__ Wse,
    const void* __restrict__ Wsl, const void* __restrict__ Wk, const void* __restrict__ Wv,
    const void* __restrict__ Wc1,
    int* __restrict__ flag, float* __restrict__ part,
    u16* __restrict__ Wsa_t, u16* __restrict__ Wse_t, u16* __restrict__ Wp_t, u16* __restrict__ Wc1t) {
  __shared__ u16 T[80 * 130];
  __shared__ float S0[256], Q0[256], S1[256], Q1[256];
  __shared__ int cnt[2];
  int tid = threadIdx.x;
  if (tid < 2) cnt[tid] = 0;
  __syncthreads();
  {   // local dtype detection (all blocks, first 1KB of s)
    u32 wv = ((const u32*)s)[tid];
    u32 lo = wv & 0xffffu, e = (lo >> 7) & 0xffu;
    if (lo == 0u || lo == 0x8000u) atomicAdd(&cnt[1], 1);
    else if (e < 0x70u || e > 0x8fu) atomicAdd(&cnt[0], 1);
  }
  __syncthreads();
  bool bf = !(cnt[0] >= 64 || cnt[1] >= 192);
  if (blockIdx.x == 0 && tid == 0) *flag = bf ? 1 : 0;
  int blkr = blockIdx.x;
  if (blkr < 2048) {   // ---- stats chunk: 64 rows ----
    int n = blkr >> 8, c = blkr & 255, b0 = c << 6;
    float* p = part + (size_t)(n * 256 + c) * 160;
    {
      int f2 = tid & 31, rg = tid >> 5;          // 8 row-groups
      float s0 = 0.f, s1 = 0.f, q0 = 0.f, q1 = 0.f;
      #pragma unroll
      for (int i = 0; i < 8; i++) {
        int b = b0 + rg + 8 * i;
        float x0, x1;
        if (bf) { u32 wv = ((const u32*)s)[((size_t)n * BATCH + b) * 32 + f2]; x0 = lo2f(wv); x1 = hi2f(wv); }
        else { const float* sf = (const float*)s + ((size_t)n * BATCH + b) * 64 + 2 * f2; x0 = sf[0]; x1 = sf[1]; }
        s0 += x0; q0 += x0 * x0; s1 += x1; q1 += x1 * x1;
      }
      S0[tid] = s0; Q0[tid] = q0; S1[tid] = s1; Q1[tid] = q1;
    }
    __syncthreads();
    if (tid < 64) {
      int f2 = tid >> 1, odd = tid & 1;
      float S = 0.f, Q = 0.f;
      #pragma unroll
      for (int rg = 0; rg < 8; rg++) {
        int ix = rg * 32 + f2;
        S += odd ? S1[ix] : S0[ix];
        Q += odd ? Q1[ix] : Q0[ix];
      }
      p[tid * 2] = S; p[tid * 2 + 1] = Q;        // feature tid
    }
    __syncthreads();
    {
      int f2 = tid & 7, rg = tid >> 3;           // 32 row-groups
      float s0 = 0.f, s1 = 0.f, q0 = 0.f, q1 = 0.f;
      #pragma unroll
      for (int i = 0; i < 2; i++) {
        int b = b0 + rg + 32 * i;
        float x0, x1;
        if (bf) { u32 wv = ((const u32*)a)[((size_t)n * BATCH + b) * 8 + f2]; x0 = lo2f(wv); x1 = hi2f(wv); }
        else { const float* af = (const float*)a + ((size_t)n * BATCH + b) * 16 + 2 * f2; x0 = af[0]; x1 = af[1]; }
        s0 += x0; q0 += x0 * x0; s1 += x1; q1 += x1 * x1;
      }
      S0[tid] = s0; Q0[tid] = q0; S1[tid] = s1; Q1[tid] = q1;
    }
    __syncthreads();
    if (tid < 16) {
      int f2 = tid >> 1, odd = tid & 1;
      float S = 0.f, Q = 0.f;
      #pragma unroll
      for (int rg = 0; rg < 32; rg++) {
        int ix = rg * 8 + f2;
        S += odd ? S1[ix] : S0[ix];
        Q += odd ? Q1[ix] : Q0[ix];
      }
      p[(SD + tid) * 2] = S; p[(SD + tid) * 2 + 1] = Q;   // feature 64+tid
    }
    return;
  }
  int blk = blkr - 2048;   // ---- weight prep ----
  if (blk < 32) {                       // Wc1 [n][256][128] -> Wc1t [n][128][256]
    int n = blk >> 2, k0 = (blk & 3) * 64;
    for (int i = tid; i < 64 * 128; i += 256) {
      int kr = i >> 7, cc = i & 127;
      T[kr * 130 + cc] = ldbf(Wc1, ((size_t)n * 256 + k0 + kr) * 128 + cc, bf);
    }
    __syncthreads();
    for (int i = tid; i < 128 * 64; i += 256) {
      int col = i >> 6, kk = i & 63;
      Wc1t[((size_t)n * 128 + col) * 256 + k0 + kk] = T[kk * 130 + col];
    }
  } else if (blk < 40) {                // Wsa -> Wsa_t
    int n = blk - 32;
    for (int i = tid; i < 80 * 128; i += 256) {
      int kr = i >> 7, cc = i & 127;
      T[kr * 130 + cc] = ldbf(Wsa, ((size_t)n * IND + kr) * 128 + cc, bf);
    }
    __syncthreads();
    for (int i = tid; i < 128 * KP3; i += 256) {
      int col = i / KP3, k = i - col * KP3;
      Wsa_t[((size_t)n * 128 + col) * KP3 + k] = (k < IND) ? T[k * 130 + col] : (u16)0;
    }
  } else if (blk < 48) {                // Wse -> Wse_t
    int n = blk - 40;
    for (int i = tid; i < 64 * 128; i += 256) {
      int kr = i >> 7, cc = i & 127;
      T[kr * 130 + cc] = ldbf(Wse, ((size_t)n * SD + kr) * 128 + cc, bf);
    }
    __syncthreads();
    for (int i = tid; i < 128 * KPS; i += 256) {
      int col = i / KPS, k = i - col * KPS;
      Wse_t[((size_t)n * 128 + col) * KPS + k] = (k < SD) ? T[k * 130 + col] : (u16)0;
    }
  } else {                              // Wp -> Wp_t [mat][col=p*32+d][KP]
    int pm = blk - 48, p = pm / 3, mat = pm - 3 * p;
    const void* W = (mat == 0) ? Wsl : (mat == 1) ? Wk : Wv;
    for (int i = tid; i < 128 * 32; i += 256) {
      int kr = i >> 5, d = i & 31;
      T[kr * 34 + d] = ldbf(W, ((size_t)p * HID + kr) * ATT + d, bf);
    }
    __syncthreads();
    for (int i = tid; i < 32 * KP; i += 256) {
      int d = i / KP, k = i - d * KP;
      Wp_t[((size_t)mat * HID + p * ATT + d) * KP + k] = (k < HID) ? T[k * 34 + d] : (u16)0;
    }
  }
}

// ---------------- K1b: fold stats partials (coalesced) -> mst_g[8][80][2] ----------------
__global__ __launch_bounds__(256) void k_fin(const float* __restrict__ part, float* __restrict__ mst_g) {
  int n = blockIdx.x;
  int t = threadIdx.x;
  if (t < 160) {   // t = f*2 + (0=S,1=Q); consecutive t -> consecutive addresses
    const float* p = part + (size_t)n * 256 * 160 + t;
    float acc = 0.f;
    #pragma unroll 8
    for (int c = 0; c < 256; c++) acc += p[(size_t)c * 160];
    float other = __shfl_xor(acc, 1);
    if ((t & 1) == 0) {
      float mean = acc * (1.f / BATCH);
      float var = other * (1.f / BATCH) - mean * mean;
      mst_g[(size_t)n * 160 + t] = mean;
      mst_g[(size_t)n * 160 + t + 1] = rsqrtf(var + EPS);
    }
  }
}

// ---------------- K2: encoders + N-split fused projections, lgkm-only barriers ----------------
// 64-row blocks, 4 waves. LDS: buf 17408 + outb 17408 + mst 640 + biases 1536 = 36992 B.
__global__ __launch_bounds__(256) void k_enc6(
    const void* __restrict__ s, const void* __restrict__ a,
    const u16* __restrict__ Wsa_t, const void* __restrict__ bsa,
    const u16* __restrict__ Wse_t, const void* __restrict__ bse,
    const u16* __restrict__ Wp_t, const void* __restrict__ bv_g,
    const float* __restrict__ mst_g, const int* __restrict__ flag,
    u16* __restrict__ SEo, u16* __restrict__ SELo, u16* __restrict__ KEYo, u16* __restrict__ VALo) {
  __shared__ __align__(16) u16 buf[64 * KP];    // sanb (stride KP3) -> KEY -> VAL -> SEL
  __shared__ __align__(16) u16 outb[64 * KP];   // E -> SE
  __shared__ float mst[IND * 2];
  __shared__ float bsaf[HID], bsef[HID], bvf[HID];
  bool bf = (*flag != 0);
  int tid = threadIdx.x;
  int n = blockIdx.y;
  int b0 = blockIdx.x * 64;
  int w = tid >> 6, lane = tid & 63, q = lane >> 4, rl = lane & 15;
  if (tid < HID) {
    bsaf[tid] = ldin(bsa, n * HID + tid, bf);
    bsef[tid] = ldin(bse, n * HID + tid, bf);
    bvf[tid]  = ldin(bv_g, tid, bf);
  }
  if (tid < IND * 2) mst[tid] = mst_g[(size_t)n * IND * 2 + tid];
  barlg();   // B0: mst/biases ready
  for (int i = tid; i < 64 * 32; i += 256) {          // s-part k 0..63
    int row = i >> 5, kp = i & 31;
    float x0, x1;
    if (bf) { u32 wv = ((const u32*)s)[((size_t)n * BATCH + b0 + row) * 32 + kp]; x0 = lo2f(wv); x1 = hi2f(wv); }
    else { const float* sf = (const float*)s + ((size_t)n * BATCH + b0 + row) * 64 + 2 * kp; x0 = sf[0]; x1 = sf[1]; }
    int k = 2 * kp;
    u32 o = (u32)f2bf((x0 - mst[k * 2]) * mst[k * 2 + 1]) |
            ((u32)f2bf((x1 - mst[k * 2 + 2]) * mst[k * 2 + 3]) << 16);
    *(u32*)&buf[row * KP3 + k] = o;
  }
  for (int i = tid; i < 64 * 8; i += 256) {           // a-part k 64..79
    int row = i >> 3, kp = i & 7;
    float x0, x1;
    if (bf) { u32 wv = ((const u32*)a)[((size_t)n * BATCH + b0 + row) * 8 + kp]; x0 = lo2f(wv); x1 = hi2f(wv); }
    else { const float* af = (const float*)a + ((size_t)n * BATCH + b0 + row) * 16 + 2 * kp; x0 = af[0]; x1 = af[1]; }
    int k = SD + 2 * kp;
    u32 o = (u32)f2bf((x0 - mst[k * 2]) * mst[k * 2 + 1]) |
            ((u32)f2bf((x1 - mst[k * 2 + 2]) * mst[k * 2 + 3]) << 16);
    *(u32*)&buf[row * KP3 + k] = o;
  }
  for (int i = tid; i < 64 * 12; i += 256) {          // zero pad k 80..103
    int row = i / 12, c2 = i - row * 12;
    *(u32*)&buf[row * KP3 + IND + 2 * c2] = 0u;
  }
  barlg();   // B1: sanb staged
  const u16* WA = Wsa_t + (size_t)n * HID * KP3;
  const u16* WS = Wse_t + (size_t)n * HID * KPS;
  // E acc (K=96) and SE acc (K=64), M-split (wave w owns rows 16w..16w+15)
  float4f accE[8] = {};
  #pragma unroll
  for (int kc = 0; kc < 3; kc++) {
    short8 a0 = *(const short8*)&buf[(w * 16 + rl) * KP3 + kc * 32 + q * 8];
    #pragma unroll
    for (int nt = 0; nt < 8; nt++) {
      short8 bb = *(const short8*)(WA + (size_t)(nt * 16 + rl) * KP3 + kc * 32 + q * 8);
      accE[nt] = MFMA16(a0, bb, accE[nt]);
    }
  }
  float4f accS[8] = {};
  #pragma unroll
  for (int kc = 0; kc < 2; kc++) {
    short8 a0 = *(const short8*)&buf[(w * 16 + rl) * KP3 + kc * 32 + q * 8];
    #pragma unroll
    for (int nt = 0; nt < 8; nt++) {
      short8 bb = *(const short8*)(WS + (size_t)(nt * 16 + rl) * KPS + kc * 32 + q * 8);
      accS[nt] = MFMA16(a0, bb, accS[nt]);
    }
  }
  barlg();   // B2: sanb reads done
  // outb <- E (wave-private rows); accE dies
  #pragma unroll
  for (int nt = 0; nt < 8; nt++)
    #pragma unroll
    for (int r = 0; r < 4; r++) {
      int row = w * 16 + q * 4 + r, col = nt * 16 + rl;
      outb[row * KP + col] = f2bf(lrelu(accE[nt][r] + bsaf[col]));
    }
  barlg();   // B2b: E tile fully visible (proj A-frags read ALL rows)
  const size_t gb = ((size_t)n * BATCH + b0) * HID;
  const u16* WSL = Wp_t;                               // mat 0, [128][KP]
  const u16* WKm = Wp_t + (size_t)HID * KP;            // mat 1
  const u16* WVm = Wp_t + (size_t)2 * HID * KP;        // mat 2
  // ---- KEY pass (N-split) -> buf ----
  {
    float4f ack[4][2] = {};
    #pragma unroll
    for (int kc = 0; kc < 4; kc++) {
      short8 af[4];
      #pragma unroll
      for (int mt = 0; mt < 4; mt++)
        af[mt] = lds_s8(&outb[(mt * 16 + rl) * KP + kc * 32 + q * 8]);
      #pragma unroll
      for (int nt = 0; nt < 2; nt++) {
        short8 bk = *(const short8*)(WKm + (size_t)(w * 32 + nt * 16 + rl) * KP + kc * 32 + q * 8);
        #pragma unroll
        for (int mt = 0; mt < 4; mt++)
          ack[mt][nt] = MFMA16(af[mt], bk, ack[mt][nt]);
      }
    }
    #pragma unroll
    for (int mt = 0; mt < 4; mt++)
      #pragma unroll
      for (int nt = 0; nt < 2; nt++)
        #pragma unroll
        for (int r = 0; r < 4; r++) {
          int row = mt * 16 + q * 4 + r, col = w * 32 + nt * 16 + rl;
          buf[row * KP + col] = f2bf(ack[mt][nt][r]);
        }
  }
  barlg();   // B3: KEY tile visible
  #pragma unroll
  for (int t = 0; t < 4; t++) {       // wide-store KEY (1KB contiguous per wave-inst)
    int idx = tid + t * 256;
    int row = idx >> 4, cc = idx & 15;
    *(short8*)(KEYo + gb + row * HID + cc * 8) = lds_s8(&buf[row * KP + cc * 8]);
  }
  barlg();   // B4: KEY store LDS-reads done (stores stay in flight)
  // ---- VAL pass (N-split, reads E from outb) -> buf ----
  {
    float4f av[4][2] = {};
    #pragma unroll
    for (int kc = 0; kc < 4; kc++) {
      short8 af[4];
      #pragma unroll
      for (int mt = 0; mt < 4; mt++)
        af[mt] = lds_s8(&outb[(mt * 16 + rl) * KP + kc * 32 + q * 8]);
      #pragma unroll
      for (int nt = 0; nt < 2; nt++) {
        short8 bv8 = *(const short8*)(WVm + (size_t)(w * 32 + nt * 16 + rl) * KP + kc * 32 + q * 8);
        #pragma unroll
        for (int mt = 0; mt < 4; mt++)
          av[mt][nt] = MFMA16(af[mt], bv8, av[mt][nt]);
      }
    }
    #pragma unroll
    for (int mt = 0; mt < 4; mt++)
      #pragma unroll
      for (int nt = 0; nt < 2; nt++)
        #pragma unroll
        for (int r = 0; r < 4; r++) {
          int row = mt * 16 + q * 4 + r, col = w * 32 + nt * 16 + rl;
          buf[row * KP + col] = f2bf(lrelu(av[mt][nt][r] + bvf[col]));
        }
  }
  barlg();   // B5: VAL tile visible + all E reads done (outb free)
  #pragma unroll
  for (int t = 0; t < 4; t++) {       // wide-store VAL
    int idx = tid + t * 256;
    int row = idx >> 4, cc = idx & 15;
    *(short8*)(VALo + gb + row * HID + cc * 8) = lds_s8(&buf[row * KP + cc * 8]);
  }
  // outb <- SE (wave-private rows); accS dies
  #pragma unroll
  for (int nt = 0; nt < 8; nt++)
    #pragma unroll
    for (int r = 0; r < 4; r++) {
      int row = w * 16 + q * 4 + r, col = nt * 16 + rl;
      outb[row * KP + col] = f2bf(lrelu(accS[nt][r] + bsef[col]));
    }
  barlg();   // B6: SE visible + VAL store LDS-reads done
  // ---- SEL pass (N-split, reads SE from outb) -> buf ----
  {
    float4f al[4][2] = {};
    #pragma unroll
    for (int kc = 0; kc < 4; kc++) {
      short8 af[4];
      #pragma unroll
      for (int mt = 0; mt < 4; mt++)
        af[mt] = lds_s8(&outb[(mt * 16 + rl) * KP + kc * 32 + q * 8]);
      #pragma unroll
      for (int nt = 0; nt < 2; nt++) {
        short8 bl = *(const short8*)(WSL + (size_t)(w * 32 + nt * 16 + rl) * KP + kc * 32 + q * 8);
        #pragma unroll
        for (int mt = 0; mt < 4; mt++)
          al[mt][nt] = MFMA16(af[mt], bl, al[mt][nt]);
      }
    }
    #pragma unroll
    for (int mt = 0; mt < 4; mt++)
      #pragma unroll
      for (int nt = 0; nt < 2; nt++)
        #pragma unroll
        for (int r = 0; r < 4; r++) {
          int row = mt * 16 + q * 4 + r, col = w * 32 + nt * 16 + rl;
          buf[row * KP + col] = f2bf(al[mt][nt][r]);
        }
  }
  barlg();   // B7: SEL tile visible
  #pragma unroll
  for (int t = 0; t < 4; t++) {       // wide-store SEL + SE
    int idx = tid + t * 256;
    int row = idx >> 4, cc = idx & 15;
    *(short8*)(SELo + gb + row * HID + cc * 8) = lds_s8(&buf[row * KP + cc * 8]);
    *(short8*)(SEo + gb + row * HID + cc * 8) = lds_s8(&outb[row * KP + cc * 8]);
  }
}

// ---------------- K3: attention, output in-place into SEL ----------------
// LDS: valt 17408 + wb 3072 = 20480 B -> 7 blocks/CU.
// SELO deliberately NOT __restrict__: reads of head p precede writes of head p.
__global__ __launch_bounds__(256) void k_attn(
    u16* SELO, const u16* __restrict__ KEY, const u16* __restrict__ VAL) {
  __shared__ __align__(16) u16 valt[HEADS * ATT * VTS];   // [p*32+d][row'=b*8+j]
  __shared__ u16 wb[64 * WBS];                            // softmax weights, wave-private rows
  int tid = threadIdx.x;
  int b0 = blockIdx.x * 8;
  int w = tid >> 6, lane = tid & 63, q = lane >> 4, rl = lane & 15;
  // stage VAL -> valt (transposed for the PV B-operand)
  {
    const u32* vu = (const u32*)VAL;
    #pragma unroll
    for (int t = 0; t < 16; t++) {
      int idx = tid + t * 256;
      int rp = idx >> 6, c2 = idx & 63;   // rp = b*8 + agent
      u32 wv = vu[((size_t)(rp & 7) * BATCH + b0 + (rp >> 3)) * 64 + c2];
      int c = 2 * c2;
      valt[c * VTS + rp] = (u16)(wv & 0xffffu);
      valt[(c + 1) * VTS + rp] = (u16)(wv >> 16);
    }
  }
  barlg();   // the only barrier
  const float scale = 0.17677669529663687f;
  // this lane's frag row': w*16+rl = b*8 + agent
  int j8 = rl & 7, bq = 2 * w + (rl >> 3);
  const size_t fbase = ((size_t)j8 * BATCH + b0 + bq) * HID;
  #pragma unroll
  for (int p = 0; p < HEADS; p++) {
    short8 sa = *(const short8*)(SELO + fbase + p * ATT + q * 8);
    short8 kb = *(const short8*)(KEY + fbase + p * ATT + q * 8);
    float4f zc = {};
    float4f c = MFMA16(sa, kb, zc);
    int nn = rl;
    #pragma unroll
    for (int r = 0; r < 4; r++) {
      int row = q * 4 + r;
      float x = c[r] * scale;
      if (row == nn) x = -1e9f;                    // self-mask (same b, i==j)
      float mx = x;
      mx = fmaxf(mx, __shfl_xor(mx, 1));
      mx = fmaxf(mx, __shfl_xor(mx, 2));
      mx = fmaxf(mx, __shfl_xor(mx, 4));
      float e = __expf(x - mx);
      float ssum = e;
      ssum += __shfl_xor(ssum, 1);
      ssum += __shfl_xor(ssum, 2);
      ssum += __shfl_xor(ssum, 4);
      float wv = e / ssum;
      if ((row >> 3) != (nn >> 3)) wv = 0.f;       // zero cross-b junk
      wb[(w * 16 + row) * WBS + nn] = f2bf(wv);    // wave-private rows
    }
    short8 aw;
    if (q < 2) aw = *(const short8*)&wb[(w * 16 + rl) * WBS + q * 8];
    else { short8 z = {}; aw = z; }
    float4f o[2] = {};
    #pragma unroll
    for (int nt = 0; nt < 2; nt++) {
      short8 bv8 = lds_s8(&valt[(p * ATT + nt * 16 + rl) * VTS + w * 16 + (q & 1) * 8]);
      o[nt] = MFMA16(aw, bv8, o[nt]);
    }
    #pragma unroll
    for (int nt = 0; nt < 2; nt++)
      #pragma unroll
      for (int r = 0; r < 4; r++) {
        int row = q * 4 + r;
        int b = 2 * w + (row >> 3), i = row & 7;
        SELO[((size_t)i * BATCH + b0 + b) * HID + p * ATT + nt * 16 + rl] = f2bf(o[nt][r]);
      }
  }
}

// ---------------- K4: critic MFMA GEMM + argmax gather, lgkm-only barriers ----------------
// LDS: Xt 34816 + wc2f 8192 + bc1f 512 + amax 512 = 44032 B
__global__ __launch_bounds__(256) void k_critic(
    const u16* __restrict__ SEi, const u16* __restrict__ OT, const void* __restrict__ a_g,
    const u16* __restrict__ Wc1t, const void* __restrict__ bc1_g,
    const void* __restrict__ Wc2_g, const void* __restrict__ bc2_g,
    const int* __restrict__ flag, void* __restrict__ qo) {
  __shared__ __align__(16) u16 Xt[128 * KP];   // input rows; reused as ht
  __shared__ float wc2f[HID * AD];
  __shared__ float bc1f[HID];
  __shared__ int amax[128];
  bool bf = (*flag != 0);
  int tid = threadIdx.x;
  int n = blockIdx.y;
  int b0 = blockIdx.x * 128;
  int w = tid >> 6, lane = tid & 63, q = lane >> 4, rl = lane & 15;
  if (tid < HID) bc1f[tid] = ldin(bc1_g, n * HID + tid, bf);
  const u16* WT = Wc1t + (size_t)n * HID * 256;

  float4f acc[2][8] = {};
  for (int ph = 0; ph < 2; ph++) {
    const u32* su = (const u32*)(ph == 0 ? SEi : OT);
    for (int idx = tid; idx < 128 * 64; idx += 256) {
      int row = idx >> 6, c = idx & 63;
      ((u32*)&Xt[row * KP])[c] = su[((size_t)n * BATCH + b0 + row) * 64 + c];
    }
    barlg();
    #pragma unroll
    for (int kc = 0; kc < 4; kc++) {
      int ko = ph * HID + kc * 32;
      short8 a0 = *(const short8*)&Xt[((2 * w) * 16 + rl) * KP + kc * 32 + q * 8];
      short8 a1 = *(const short8*)&Xt[((2 * w + 1) * 16 + rl) * KP + kc * 32 + q * 8];
      #pragma unroll
      for (int nt = 0; nt < 8; nt++) {
        short8 bb = *(const short8*)(WT + (size_t)(nt * 16 + rl) * 256 + ko + q * 8);
        acc[0][nt] = MFMA16(a0, bb, acc[0][nt]);
        acc[1][nt] = MFMA16(a1, bb, acc[1][nt]);
      }
    }
    barlg();
  }
  u16* ht = Xt;
  #pragma unroll
  for (int mi = 0; mi < 2; mi++)
    #pragma unroll
    for (int nt = 0; nt < 8; nt++)
      #pragma unroll
      for (int r = 0; r < 4; r++) {
        int row = (2 * w + mi) * 16 + q * 4 + r, col = nt * 16 + rl;
        ht[row * KP + col] = f2bf(lrelu(acc[mi][nt][r] + bc1f[col]));
      }
  for (int idx = tid; idx < HID * AD; idx += 256)
    wc2f[idx] = ldin(Wc2_g, (size_t)n * HID * AD + idx, bf);
  if (tid < 128) {
    size_t base = ((size_t)n * BATCH + b0 + tid) * AD;
    float best = ldin(a_g, base, bf); int bi = 0;
    for (int o = 1; o < AD; o++) {
      float v = ldin(a_g, base + o, bf);
      if (v > best) { best = v; bi = o; }   // strict > = first-max
    }
    amax[tid] = bi;
  }
  barlg();
  {
    int b = tid >> 1, half = tid & 1;
    int col = amax[b];
    float acq = 0.f;
    const u16* hr = &ht[b * KP + half * 64];
    #pragma unroll
    for (int k = 0; k < 64; k++)
      acq = fmaf(bf2f(hr[k]), wc2f[(half * 64 + k) * AD + col], acq);
    acq += __shfl_xor(acq, 1);
    if (half == 0) {
      float v = acq + ldin(bc2_g, n * AD + col, bf);
      size_t oidx = (size_t)n * BATCH + b0 + b;
      if (bf) ((u16*)qo)[oidx] = f2bf(v);
      else    ((float*)qo)[oidx] = v;
    }
  }
}

extern "C" void kernel_launch(void* const* d_in, const int* in_sizes, int n_in,
                              void* d_out, int out_size, void* d_ws, size_t ws_size,
                              hipStream_t stream) {
  const void* s   = d_in[0];
  const void* a   = d_in[1];
  const void* Wsa = d_in[2];
  const void* bsa = d_in[3];
  const void* Wse = d_in[4];
  const void* bse = d_in[5];
  const void* Wk  = d_in[6];
  const void* Wsl = d_in[7];
  const void* Wv  = d_in[8];
  const void* bv  = d_in[9];
  const void* Wc1 = d_in[10];
  const void* bc1 = d_in[11];
  const void* Wc2 = d_in[12];
  const void* bc2 = d_in[13];

  char* ws = (char*)d_ws;
  int*   flag  = (int*)ws;
  float* part  = (float*)(ws + 1024);
  float* mst_g = (float*)(ws + 1311744);
  u16*   Wsa_t = (u16*)(ws + 1316864);
  u16*   Wse_t = (u16*)(ws + 1529856);
  u16*   Wp_t  = (u16*)(ws + 1677312);
  u16*   Wc1t  = (u16*)(ws + 1781760);
  u16*   SEb   = (u16*)(ws + 2306048);
  u16*   SEL   = (u16*)(ws + 2306048 + 1ull * 33554432ull);
  u16*   KEY   = (u16*)(ws + 2306048 + 2ull * 33554432ull);
  u16*   VAL   = (u16*)(ws + 2306048 + 3ull * 33554432ull);

  k_prep2<<<2108, 256, 0, stream>>>(s, a, Wsa, Wse, Wsl, Wk, Wv, Wc1,
                                    flag, part, Wsa_t, Wse_t, Wp_t, Wc1t);
  k_fin<<<NA, 256, 0, stream>>>(part, mst_g);
  k_enc6<<<dim3(BATCH / 64, NA), 256, 0, stream>>>(s, a, Wsa_t, bsa, Wse_t, bse, Wp_t, bv,
                                                   mst_g, flag, SEb, SEL, KEY, VAL);
  k_attn<<<BATCH / 8, 256, 0, stream>>>(SEL, KEY, VAL);
  k_critic<<<dim3(BATCH / 128, NA), 256, 0, stream>>>(SEb, SEL, a, Wc1t, bc1, Wc2, bc2, flag, d_out);
}

// Round 5
// 262.617 us; speedup vs baseline: 1.1192x; 1.1192x over previous
//
#include <hip/hip_runtime.h>

// Attention_Critic on MI355X — round 14: kill enc spills + interleaved attn layout.
//  - k_enc7: sequential phases, ONE live accumulator at a time (accS retired
//    before accE computed; proj accs transient). 4 barriers (was 8). Proj
//    outputs stored from registers. SEL/KEY/VAL written in interleaved layout
//    [b*8+agent][128] so attn reads are contiguous.
//  - k_attn2: frag row rp = w*16+rl -> each quarter-wave load = one contiguous
//    4KB block; VAL staging fully coalesced. In-place OT write into SEL2.
//  - k_critic: OT staged from interleaved layout (256B-contiguous rows).
//  - k_prep2 / k_fin: unchanged from round 13.
//
// ws layout (bytes):
//   [0,256)          int flag (1 = bf16 inputs, 0 = f32)
//   [1024,+1310720)  stats partials f32 [8][256][160]
//   [1311744,+5120)  mst_g f32 [8][80][2]
//   [1316864,...)    Wsa_t bf16 [8][128 col][104 k]
//   [1529856,...)    Wse_t bf16 [8][128 col][72 k]
//   [1677312,...)    Wp_t  bf16 [3 mat][128 col][136 k]  (mat 0=sel,1=key,2=val)
//   [1781760,...)    Wc1t  bf16 [8][128 col][256 k]
//   [2306048,+32M)   SE   bf16 [8][16384][128]           (agent-major)
//   [+32M,+64M)      SEL2 bf16 [16384*8][128] row=b*8+agent (attn writes OT in place)
//   [+64M,+96M)      KEY2 bf16 [16384*8][128] row=b*8+agent
//   [+96M,+128M)     VAL2 bf16 [16384*8][128] row=b*8+agent

typedef unsigned short u16;
typedef unsigned int u32;

#define NA 8
#define BATCH 16384
#define SD 64
#define AD 16
#define IND 80
#define HID 128
#define HEADS 4
#define ATT 32
#define EPS 1e-5f
#define KP 136    // u16 stride, 128-k tiles (16B-aligned rows)
#define KP3 104   // u16 stride, 96-k tiles (Wsa_t)
#define KPS 72    // u16 stride, 64-k tiles (Wse_t)
#define VTS 68    // u16 stride, valt [32 d][64 row']
#define WBS 24    // u16 stride, softmax weight tiles

using short8 = __attribute__((ext_vector_type(8))) short;
using float4f = __attribute__((ext_vector_type(4))) float;
#define MFMA16(a, b, c) __builtin_amdgcn_mfma_f32_16x16x32_bf16((a), (b), (c), 0, 0, 0)

__device__ __forceinline__ float bf2f(u16 u) { union { u32 i; float f; } v; v.i = ((u32)u) << 16; return v.f; }
__device__ __forceinline__ float lo2f(u32 w) { union { u32 i; float f; } v; v.i = w << 16; return v.f; }
__device__ __forceinline__ float hi2f(u32 w) { union { u32 i; float f; } v; v.i = w & 0xffff0000u; return v.f; }
__device__ __forceinline__ u16 f2bf(float f) {
  union { float f; u32 i; } v; v.f = f;
  u32 x = v.i;
  x += 0x7fffu + ((x >> 16) & 1u);   // RNE
  return (u16)(x >> 16);
}
__device__ __forceinline__ float lrelu(float x) { return x > 0.f ? x : 0.01f * x; }
__device__ __forceinline__ float ldin(const void* p, size_t i, bool bf) {
  return bf ? bf2f(((const u16*)p)[i]) : ((const float*)p)[i];
}
__device__ __forceinline__ u16 ldbf(const void* p, size_t i, bool bf) {
  return bf ? ((const u16*)p)[i] : f2bf(((const float*)p)[i]);
}
__device__ __forceinline__ short8 lds_s8(const u16* p) {   // 16B LDS load, 4B-aligned ok
  union { short8 v; u32 u[4]; } t;
  const u32* q = (const u32*)p;
  t.u[0] = q[0]; t.u[1] = q[1]; t.u[2] = q[2]; t.u[3] = q[3];
  return t.v;
}
// Barrier that orders LDS only: global stores stay in flight.
__device__ __forceinline__ void barlg() {
  asm volatile("s_waitcnt lgkmcnt(0)" ::: "memory");
  __builtin_amdgcn_s_barrier();
}

// ---------------- K1: merged BN stats (2048 blocks) + weight prep (60 blocks) ----------------
__global__ __launch_bounds__(256) void k_prep2(
    const void* __restrict__ s, const void* __restrict__ a,
    const void* __restrict__ Wsa, const void* __restrict__ Wse,
    const void* __restrict__ Wsl, const void* __restrict__ Wk, const void* __restrict__ Wv,
    const void* __restrict__ Wc1,
    int* __restrict__ flag, float* __restrict__ part,
    u16* __restrict__ Wsa_t, u16* __restrict__ Wse_t, u16* __restrict__ Wp_t, u16* __restrict__ Wc1t) {
  __shared__ u16 T[80 * 130];
  __shared__ float S0[256], Q0[256], S1[256], Q1[256];
  __shared__ int cnt[2];
  int tid = threadIdx.x;
  if (tid < 2) cnt[tid] = 0;
  __syncthreads();
  {   // local dtype detection (all blocks, first 1KB of s)
    u32 wv = ((const u32*)s)[tid];
    u32 lo = wv & 0xffffu, e = (lo >> 7) & 0xffu;
    if (lo == 0u || lo == 0x8000u) atomicAdd(&cnt[1], 1);
    else if (e < 0x70u || e > 0x8fu) atomicAdd(&cnt[0], 1);
  }
  __syncthreads();
  bool bf = !(cnt[0] >= 64 || cnt[1] >= 192);
  if (blockIdx.x == 0 && tid == 0) *flag = bf ? 1 : 0;
  int blkr = blockIdx.x;
  if (blkr < 2048) {   // ---- stats chunk: 64 rows ----
    int n = blkr >> 8, c = blkr & 255, b0 = c << 6;
    float* p = part + (size_t)(n * 256 + c) * 160;
    {
      int f2 = tid & 31, rg = tid >> 5;          // 8 row-groups
      float s0 = 0.f, s1 = 0.f, q0 = 0.f, q1 = 0.f;
      #pragma unroll
      for (int i = 0; i < 8; i++) {
        int b = b0 + rg + 8 * i;
        float x0, x1;
        if (bf) { u32 wv = ((const u32*)s)[((size_t)n * BATCH + b) * 32 + f2]; x0 = lo2f(wv); x1 = hi2f(wv); }
        else { const float* sf = (const float*)s + ((size_t)n * BATCH + b) * 64 + 2 * f2; x0 = sf[0]; x1 = sf[1]; }
        s0 += x0; q0 += x0 * x0; s1 += x1; q1 += x1 * x1;
      }
      S0[tid] = s0; Q0[tid] = q0; S1[tid] = s1; Q1[tid] = q1;
    }
    __syncthreads();
    if (tid < 64) {
      int f2 = tid >> 1, odd = tid & 1;
      float S = 0.f, Q = 0.f;
      #pragma unroll
      for (int rg = 0; rg < 8; rg++) {
        int ix = rg * 32 + f2;
        S += odd ? S1[ix] : S0[ix];
        Q += odd ? Q1[ix] : Q0[ix];
      }
      p[tid * 2] = S; p[tid * 2 + 1] = Q;
    }
    __syncthreads();
    {
      int f2 = tid & 7, rg = tid >> 3;           // 32 row-groups
      float s0 = 0.f, s1 = 0.f, q0 = 0.f, q1 = 0.f;
      #pragma unroll
      for (int i = 0; i < 2; i++) {
        int b = b0 + rg + 32 * i;
        float x0, x1;
        if (bf) { u32 wv = ((const u32*)a)[((size_t)n * BATCH + b) * 8 + f2]; x0 = lo2f(wv); x1 = hi2f(wv); }
        else { const float* af = (const float*)a + ((size_t)n * BATCH + b) * 16 + 2 * f2; x0 = af[0]; x1 = af[1]; }
        s0 += x0; q0 += x0 * x0; s1 += x1; q1 += x1 * x1;
      }
      S0[tid] = s0; Q0[tid] = q0; S1[tid] = s1; Q1[tid] = q1;
    }
    __syncthreads();
    if (tid < 16) {
      int f2 = tid >> 1, odd = tid & 1;
      float S = 0.f, Q = 0.f;
      #pragma unroll
      for (int rg = 0; rg < 32; rg++) {
        int ix = rg * 8 + f2;
        S += odd ? S1[ix] : S0[ix];
        Q += odd ? Q1[ix] : Q0[ix];
      }
      p[(SD + tid) * 2] = S; p[(SD + tid) * 2 + 1] = Q;
    }
    return;
  }
  int blk = blkr - 2048;   // ---- weight prep ----
  if (blk < 32) {                       // Wc1 [n][256][128] -> Wc1t [n][128][256]
    int n = blk >> 2, k0 = (blk & 3) * 64;
    for (int i = tid; i < 64 * 128; i += 256) {
      int kr = i >> 7, cc = i & 127;
      T[kr * 130 + cc] = ldbf(Wc1, ((size_t)n * 256 + k0 + kr) * 128 + cc, bf);
    }
    __syncthreads();
    for (int i = tid; i < 128 * 64; i += 256) {
      int col = i >> 6, kk = i & 63;
      Wc1t[((size_t)n * 128 + col) * 256 + k0 + kk] = T[kk * 130 + col];
    }
  } else if (blk < 40) {                // Wsa -> Wsa_t
    int n = blk - 32;
    for (int i = tid; i < 80 * 128; i += 256) {
      int kr = i >> 7, cc = i & 127;
      T[kr * 130 + cc] = ldbf(Wsa, ((size_t)n * IND + kr) * 128 + cc, bf);
    }
    __syncthreads();
    for (int i = tid; i < 128 * KP3; i += 256) {
      int col = i / KP3, k = i - col * KP3;
      Wsa_t[((size_t)n * 128 + col) * KP3 + k] = (k < IND) ? T[k * 130 + col] : (u16)0;
    }
  } else if (blk < 48) {                // Wse -> Wse_t
    int n = blk - 40;
    for (int i = tid; i < 64 * 128; i += 256) {
      int kr = i >> 7, cc = i & 127;
      T[kr * 130 + cc] = ldbf(Wse, ((size_t)n * SD + kr) * 128 + cc, bf);
    }
    __syncthreads();
    for (int i = tid; i < 128 * KPS; i += 256) {
      int col = i / KPS, k = i - col * KPS;
      Wse_t[((size_t)n * 128 + col) * KPS + k] = (k < SD) ? T[k * 130 + col] : (u16)0;
    }
  } else {                              // Wp -> Wp_t [mat][col=p*32+d][KP]
    int pm = blk - 48, p = pm / 3, mat = pm - 3 * p;
    const void* W = (mat == 0) ? Wsl : (mat == 1) ? Wk : Wv;
    for (int i = tid; i < 128 * 32; i += 256) {
      int kr = i >> 5, d = i & 31;
      T[kr * 34 + d] = ldbf(W, ((size_t)p * HID + kr) * ATT + d, bf);
    }
    __syncthreads();
    for (int i = tid; i < 32 * KP; i += 256) {
      int d = i / KP, k = i - d * KP;
      Wp_t[((size_t)mat * HID + p * ATT + d) * KP + k] = (k < HID) ? T[k * 34 + d] : (u16)0;
    }
  }
}

// ---------------- K1b: fold stats partials (coalesced) -> mst_g[8][80][2] ----------------
__global__ __launch_bounds__(256) void k_fin(const float* __restrict__ part, float* __restrict__ mst_g) {
  int n = blockIdx.x;
  int t = threadIdx.x;
  if (t < 160) {
    const float* p = part + (size_t)n * 256 * 160 + t;
    float acc = 0.f;
    #pragma unroll 8
    for (int c = 0; c < 256; c++) acc += p[(size_t)c * 160];
    float other = __shfl_xor(acc, 1);
    if ((t & 1) == 0) {
      float mean = acc * (1.f / BATCH);
      float var = other * (1.f / BATCH) - mean * mean;
      mst_g[(size_t)n * 160 + t] = mean;
      mst_g[(size_t)n * 160 + t + 1] = rsqrtf(var + EPS);
    }
  }
}

// ---------------- K2: sequential-phase encoders + N-split projections ----------------
// 64-row blocks, 4 waves. LDS: A 17408 + Bt 17408 + mst 640 + biases 1536 = 36992 B.
// One accumulator live at a time; proj outputs stored from registers.
// Barriers: B0 (mst), B1 (sanb), B2 (sanb reads done), B3 (E/SE tiles visible).
__global__ __launch_bounds__(256) void k_enc7(
    const void* __restrict__ s, const void* __restrict__ a,
    const u16* __restrict__ Wsa_t, const void* __restrict__ bsa,
    const u16* __restrict__ Wse_t, const void* __restrict__ bse,
    const u16* __restrict__ Wp_t, const void* __restrict__ bv_g,
    const float* __restrict__ mst_g, const int* __restrict__ flag,
    u16* __restrict__ SEo, u16* __restrict__ SEL2, u16* __restrict__ KEY2, u16* __restrict__ VAL2) {
  __shared__ __align__(16) u16 A[64 * KP];    // sanb (cols 0..95) -> E (cols 0..127)
  __shared__ __align__(16) u16 Bt[64 * KP];   // SE
  __shared__ float mst[IND * 2];
  __shared__ float bsaf[HID], bsef[HID], bvf[HID];
  bool bf = (*flag != 0);
  int tid = threadIdx.x;
  int n = blockIdx.y;
  int b0 = blockIdx.x * 64;
  int w = tid >> 6, lane = tid & 63, q = lane >> 4, rl = lane & 15;
  if (tid < HID) {
    bsaf[tid] = ldin(bsa, n * HID + tid, bf);
    bsef[tid] = ldin(bse, n * HID + tid, bf);
    bvf[tid]  = ldin(bv_g, tid, bf);
  }
  if (tid < IND * 2) mst[tid] = mst_g[(size_t)n * IND * 2 + tid];
  barlg();   // B0
  // ---- stage bn(s|a) into A (stride KP, cols 0..79 data, 80..95 zero) ----
  for (int i = tid; i < 64 * 32; i += 256) {          // s-part k 0..63
    int row = i >> 5, kp = i & 31;
    float x0, x1;
    if (bf) { u32 wv = ((const u32*)s)[((size_t)n * BATCH + b0 + row) * 32 + kp]; x0 = lo2f(wv); x1 = hi2f(wv); }
    else { const float* sf = (const float*)s + ((size_t)n * BATCH + b0 + row) * 64 + 2 * kp; x0 = sf[0]; x1 = sf[1]; }
    int k = 2 * kp;
    u32 o = (u32)f2bf((x0 - mst[k * 2]) * mst[k * 2 + 1]) |
            ((u32)f2bf((x1 - mst[k * 2 + 2]) * mst[k * 2 + 3]) << 16);
    *(u32*)&A[row * KP + k] = o;
  }
  for (int i = tid; i < 64 * 8; i += 256) {           // a-part k 64..79
    int row = i >> 3, kp = i & 7;
    float x0, x1;
    if (bf) { u32 wv = ((const u32*)a)[((size_t)n * BATCH + b0 + row) * 8 + kp]; x0 = lo2f(wv); x1 = hi2f(wv); }
    else { const float* af = (const float*)a + ((size_t)n * BATCH + b0 + row) * 16 + 2 * kp; x0 = af[0]; x1 = af[1]; }
    int k = SD + 2 * kp;
    u32 o = (u32)f2bf((x0 - mst[k * 2]) * mst[k * 2 + 1]) |
            ((u32)f2bf((x1 - mst[k * 2 + 2]) * mst[k * 2 + 3]) << 16);
    *(u32*)&A[row * KP + k] = o;
  }
  for (int i = tid; i < 64 * 8; i += 256) {           // zero pad k 80..95
    int row = i >> 3, c2 = i & 7;
    *(u32*)&A[row * KP + IND + 2 * c2] = 0u;
  }
  barlg();   // B1: sanb staged
  const u16* WS = Wse_t + (size_t)n * HID * KPS;
  const u16* WA = Wsa_t + (size_t)n * HID * KP3;
  // ---- phase 1: SE acc (K=64); retire immediately (global from regs + Bt tile) ----
  {
    float4f accS[8] = {};
    #pragma unroll
    for (int kc = 0; kc < 2; kc++) {
      short8 a0 = *(const short8*)&A[(w * 16 + rl) * KP + kc * 32 + q * 8];
      #pragma unroll
      for (int nt = 0; nt < 8; nt++) {
        short8 bb = *(const short8*)(WS + (size_t)(nt * 16 + rl) * KPS + kc * 32 + q * 8);
        accS[nt] = MFMA16(a0, bb, accS[nt]);
      }
    }
    #pragma unroll
    for (int nt = 0; nt < 8; nt++)
      #pragma unroll
      for (int r = 0; r < 4; r++) {
        int row = w * 16 + q * 4 + r, col = nt * 16 + rl;
        u16 v = f2bf(lrelu(accS[nt][r] + bsef[col]));
        SEo[((size_t)n * BATCH + b0 + row) * HID + col] = v;
        Bt[row * KP + col] = v;                        // wave-private rows
      }
  }
  __builtin_amdgcn_sched_barrier(0);
  // ---- phase 2: E acc (K=96) ----
  {
    float4f accE[8] = {};
    #pragma unroll
    for (int kc = 0; kc < 3; kc++) {
      short8 a0 = *(const short8*)&A[(w * 16 + rl) * KP + kc * 32 + q * 8];
      #pragma unroll
      for (int nt = 0; nt < 8; nt++) {
        short8 bb = *(const short8*)(WA + (size_t)(nt * 16 + rl) * KP3 + kc * 32 + q * 8);
        accE[nt] = MFMA16(a0, bb, accE[nt]);
      }
    }
    barlg();   // B2: ALL sanb reads done (both GEMMs, all waves)
    #pragma unroll
    for (int nt = 0; nt < 8; nt++)
      #pragma unroll
      for (int r = 0; r < 4; r++) {
        int row = w * 16 + q * 4 + r, col = nt * 16 + rl;
        A[row * KP + col] = f2bf(lrelu(accE[nt][r] + bsaf[col]));   // E over sanb
      }
  }
  barlg();   // B3: E (A) and SE (Bt) tiles fully visible
  const u16* WSL = Wp_t;                               // mat 0, [128][KP]
  const u16* WKm = Wp_t + (size_t)HID * KP;            // mat 1
  const u16* WVm = Wp_t + (size_t)2 * HID * KP;        // mat 2
  // ---- phase 3: KEY = E @ Wk (N-split), store from regs, interleaved layout ----
  {
    float4f ac[4][2] = {};
    #pragma unroll
    for (int kc = 0; kc < 4; kc++) {
      short8 af[4];
      #pragma unroll
      for (int mt = 0; mt < 4; mt++)
        af[mt] = *(const short8*)&A[(mt * 16 + rl) * KP + kc * 32 + q * 8];
      #pragma unroll
      for (int nt = 0; nt < 2; nt++) {
        short8 bk = *(const short8*)(WKm + (size_t)(w * 32 + nt * 16 + rl) * KP + kc * 32 + q * 8);
        #pragma unroll
        for (int mt = 0; mt < 4; mt++)
          ac[mt][nt] = MFMA16(af[mt], bk, ac[mt][nt]);
      }
    }
    #pragma unroll
    for (int mt = 0; mt < 4; mt++)
      #pragma unroll
      for (int nt = 0; nt < 2; nt++)
        #pragma unroll
        for (int r = 0; r < 4; r++) {
          int row = mt * 16 + q * 4 + r, col = w * 32 + nt * 16 + rl;
          KEY2[((size_t)(b0 + row) * NA + n) * HID + col] = f2bf(ac[mt][nt][r]);
        }
  }
  __builtin_amdgcn_sched_barrier(0);
  // ---- phase 4: VAL = lrelu(E @ Wv + bv) (N-split) ----
  {
    float4f ac[4][2] = {};
    #pragma unroll
    for (int kc = 0; kc < 4; kc++) {
      short8 af[4];
      #pragma unroll
      for (int mt = 0; mt < 4; mt++)
        af[mt] = *(const short8*)&A[(mt * 16 + rl) * KP + kc * 32 + q * 8];
      #pragma unroll
      for (int nt = 0; nt < 2; nt++) {
        short8 bv8 = *(const short8*)(WVm + (size_t)(w * 32 + nt * 16 + rl) * KP + kc * 32 + q * 8);
        #pragma unroll
        for (int mt = 0; mt < 4; mt++)
          ac[mt][nt] = MFMA16(af[mt], bv8, ac[mt][nt]);
      }
    }
    #pragma unroll
    for (int mt = 0; mt < 4; mt++)
      #pragma unroll
      for (int nt = 0; nt < 2; nt++)
        #pragma unroll
        for (int r = 0; r < 4; r++) {
          int row = mt * 16 + q * 4 + r, col = w * 32 + nt * 16 + rl;
          VAL2[((size_t)(b0 + row) * NA + n) * HID + col] = f2bf(lrelu(ac[mt][nt][r] + bvf[col]));
        }
  }
  __builtin_amdgcn_sched_barrier(0);
  // ---- phase 5: SEL = SE @ Wsel (N-split from Bt) ----
  {
    float4f ac[4][2] = {};
    #pragma unroll
    for (int kc = 0; kc < 4; kc++) {
      short8 af[4];
      #pragma unroll
      for (int mt = 0; mt < 4; mt++)
        af[mt] = *(const short8*)&Bt[(mt * 16 + rl) * KP + kc * 32 + q * 8];
      #pragma unroll
      for (int nt = 0; nt < 2; nt++) {
        short8 bl = *(const short8*)(WSL + (size_t)(w * 32 + nt * 16 + rl) * KP + kc * 32 + q * 8);
        #pragma unroll
        for (int mt = 0; mt < 4; mt++)
          ac[mt][nt] = MFMA16(af[mt], bl, ac[mt][nt]);
      }
    }
    #pragma unroll
    for (int mt = 0; mt < 4; mt++)
      #pragma unroll
      for (int nt = 0; nt < 2; nt++)
        #pragma unroll
        for (int r = 0; r < 4; r++) {
          int row = mt * 16 + q * 4 + r, col = w * 32 + nt * 16 + rl;
          SEL2[((size_t)(b0 + row) * NA + n) * HID + col] = f2bf(ac[mt][nt][r]);
        }
  }
}

// ---------------- K3: attention on interleaved layout, in-place OT ----------------
// LDS: valt 17408 + wb 3072 = 20480 B -> 7 blocks/CU.
// SELO not __restrict__: reads of head p precede writes of head p (same rows).
__global__ __launch_bounds__(256) void k_attn2(
    u16* SELO, const u16* __restrict__ KEY, const u16* __restrict__ VAL) {
  __shared__ __align__(16) u16 valt[HEADS * ATT * VTS];   // [p*32+d][row'=b*8+j]
  __shared__ u16 wb[64 * WBS];                            // softmax weights, wave-private rows
  int tid = threadIdx.x;
  size_t r0 = (size_t)blockIdx.x * 64;                    // first interleaved row (8 batches x 8 agents)
  int w = tid >> 6, lane = tid & 63, q = lane >> 4, rl = lane & 15;
  // stage VAL -> valt (transposed; source fully coalesced)
  {
    const u32* vu = (const u32*)VAL;
    #pragma unroll
    for (int t = 0; t < 16; t++) {
      int idx = tid + t * 256;
      int rp = idx >> 6, c2 = idx & 63;   // rp = b*8 + agent
      u32 wv = vu[(r0 + rp) * 64 + c2];
      int c = 2 * c2;
      valt[c * VTS + rp] = (u16)(wv & 0xffffu);
      valt[(c + 1) * VTS + rp] = (u16)(wv >> 16);
    }
  }
  barlg();   // the only barrier
  const float scale = 0.17677669529663687f;
  // lane's frag row rp = w*16+rl (contiguous 4KB per quarter-wave)
  const size_t fbase = (r0 + w * 16 + rl) * HID;
  #pragma unroll
  for (int p = 0; p < HEADS; p++) {
    short8 sa = *(const short8*)(SELO + fbase + p * ATT + q * 8);
    short8 kb = *(const short8*)(KEY + fbase + p * ATT + q * 8);
    float4f zc = {};
    float4f c = MFMA16(sa, kb, zc);
    int nn = rl;
    #pragma unroll
    for (int r = 0; r < 4; r++) {
      int row = q * 4 + r;
      float x = c[r] * scale;
      if (row == nn) x = -1e9f;                    // self-mask (same b, i==j)
      float mx = x;
      mx = fmaxf(mx, __shfl_xor(mx, 1));
      mx = fmaxf(mx, __shfl_xor(mx, 2));
      mx = fmaxf(mx, __shfl_xor(mx, 4));
      float e = __expf(x - mx);
      float ssum = e;
      ssum += __shfl_xor(ssum, 1);
      ssum += __shfl_xor(ssum, 2);
      ssum += __shfl_xor(ssum, 4);
      float wv = e / ssum;
      if ((row >> 3) != (nn >> 3)) wv = 0.f;       // zero cross-b junk
      wb[(w * 16 + row) * WBS + nn] = f2bf(wv);    // wave-private rows
    }
    short8 aw;
    if (q < 2) aw = *(const short8*)&wb[(w * 16 + rl) * WBS + q * 8];
    else { short8 z = {}; aw = z; }
    float4f o[2] = {};
    #pragma unroll
    for (int nt = 0; nt < 2; nt++) {
      short8 bv8 = lds_s8(&valt[(p * ATT + nt * 16 + rl) * VTS + w * 16 + (q & 1) * 8]);
      o[nt] = MFMA16(aw, bv8, o[nt]);
    }
    #pragma unroll
    for (int nt = 0; nt < 2; nt++)
      #pragma unroll
      for (int r = 0; r < 4; r++) {
        int row = q * 4 + r;
        int rp = w * 16 + (row >> 3) * 8 + (row & 7);   // b*8 + agent
        SELO[(r0 + rp) * HID + p * ATT + nt * 16 + rl] = f2bf(o[nt][r]);
      }
  }
}

// ---------------- K4: critic MFMA GEMM + argmax gather (OT from interleaved layout) ----------------
// LDS: Xt 34816 + wc2f 8192 + bc1f 512 + amax 512 = 44032 B
__global__ __launch_bounds__(256) void k_critic(
    const u16* __restrict__ SEi, const u16* __restrict__ OT, const void* __restrict__ a_g,
    const u16* __restrict__ Wc1t, const void* __restrict__ bc1_g,
    const void* __restrict__ Wc2_g, const void* __restrict__ bc2_g,
    const int* __restrict__ flag, void* __restrict__ qo) {
  __shared__ __align__(16) u16 Xt[128 * KP];   // input rows; reused as ht
  __shared__ float wc2f[HID * AD];
  __shared__ float bc1f[HID];
  __shared__ int amax[128];
  bool bf = (*flag != 0);
  int tid = threadIdx.x;
  int n = blockIdx.y;
  int b0 = blockIdx.x * 128;
  int w = tid >> 6, lane = tid & 63, q = lane >> 4, rl = lane & 15;
  if (tid < HID) bc1f[tid] = ldin(bc1_g, n * HID + tid, bf);
  const u16* WT = Wc1t + (size_t)n * HID * 256;

  float4f acc[2][8] = {};
  for (int ph = 0; ph < 2; ph++) {
    for (int idx = tid; idx < 128 * 64; idx += 256) {
      int row = idx >> 6, c = idx & 63;
      u32 wv;
      if (ph == 0) wv = ((const u32*)SEi)[((size_t)n * BATCH + b0 + row) * 64 + c];
      else         wv = ((const u32*)OT)[((size_t)(b0 + row) * NA + n) * 64 + c];
      ((u32*)&Xt[row * KP])[c] = wv;
    }
    barlg();
    #pragma unroll
    for (int kc = 0; kc < 4; kc++) {
      int ko = ph * HID + kc * 32;
      short8 a0 = *(const short8*)&Xt[((2 * w) * 16 + rl) * KP + kc * 32 + q * 8];
      short8 a1 = *(const short8*)&Xt[((2 * w + 1) * 16 + rl) * KP + kc * 32 + q * 8];
      #pragma unroll
      for (int nt = 0; nt < 8; nt++) {
        short8 bb = *(const short8*)(WT + (size_t)(nt * 16 + rl) * 256 + ko + q * 8);
        acc[0][nt] = MFMA16(a0, bb, acc[0][nt]);
        acc[1][nt] = MFMA16(a1, bb, acc[1][nt]);
      }
    }
    barlg();
  }
  u16* ht = Xt;
  #pragma unroll
  for (int mi = 0; mi < 2; mi++)
    #pragma unroll
    for (int nt = 0; nt < 8; nt++)
      #pragma unroll
      for (int r = 0; r < 4; r++) {
        int row = (2 * w + mi) * 16 + q * 4 + r, col = nt * 16 + rl;
        ht[row * KP + col] = f2bf(lrelu(acc[mi][nt][r] + bc1f[col]));
      }
  for (int idx = tid; idx < HID * AD; idx += 256)
    wc2f[idx] = ldin(Wc2_g, (size_t)n * HID * AD + idx, bf);
  if (tid < 128) {
    size_t base = ((size_t)n * BATCH + b0 + tid) * AD;
    float best = ldin(a_g, base, bf); int bi = 0;
    for (int o = 1; o < AD; o++) {
      float v = ldin(a_g, base + o, bf);
      if (v > best) { best = v; bi = o; }   // strict > = first-max
    }
    amax[tid] = bi;
  }
  barlg();
  {
    int b = tid >> 1, half = tid & 1;
    int col = amax[b];
    float acq = 0.f;
    const u16* hr = &ht[b * KP + half * 64];
    #pragma unroll
    for (int k = 0; k < 64; k++)
      acq = fmaf(bf2f(hr[k]), wc2f[(half * 64 + k) * AD + col], acq);
    acq += __shfl_xor(acq, 1);
    if (half == 0) {
      float v = acq + ldin(bc2_g, n * AD + col, bf);
      size_t oidx = (size_t)n * BATCH + b0 + b;
      if (bf) ((u16*)qo)[oidx] = f2bf(v);
      else    ((float*)qo)[oidx] = v;
    }
  }
}

extern "C" void kernel_launch(void* const* d_in, const int* in_sizes, int n_in,
                              void* d_out, int out_size, void* d_ws, size_t ws_size,
                              hipStream_t stream) {
  const void* s   = d_in[0];
  const void* a   = d_in[1];
  const void* Wsa = d_in[2];
  const void* bsa = d_in[3];
  const void* Wse = d_in[4];
  const void* bse = d_in[5];
  const void* Wk  = d_in[6];
  const void* Wsl = d_in[7];
  const void* Wv  = d_in[8];
  const void* bv  = d_in[9];
  const void* Wc1 = d_in[10];
  const void* bc1 = d_in[11];
  const void* Wc2 = d_in[12];
  const void* bc2 = d_in[13];

  char* ws = (char*)d_ws;
  int*   flag  = (int*)ws;
  float* part  = (float*)(ws + 1024);
  float* mst_g = (float*)(ws + 1311744);
  u16*   Wsa_t = (u16*)(ws + 1316864);
  u16*   Wse_t = (u16*)(ws + 1529856);
  u16*   Wp_t  = (u16*)(ws + 1677312);
  u16*   Wc1t  = (u16*)(ws + 1781760);
  u16*   SEb   = (u16*)(ws + 2306048);
  u16*   SEL   = (u16*)(ws + 2306048 + 1ull * 33554432ull);
  u16*   KEY   = (u16*)(ws + 2306048 + 2ull * 33554432ull);
  u16*   VAL   = (u16*)(ws + 2306048 + 3ull * 33554432ull);

  k_prep2<<<2108, 256, 0, stream>>>(s, a, Wsa, Wse, Wsl, Wk, Wv, Wc1,
                                    flag, part, Wsa_t, Wse_t, Wp_t, Wc1t);
  k_fin<<<NA, 256, 0, stream>>>(part, mst_g);
  k_enc7<<<dim3(BATCH / 64, NA), 256, 0, stream>>>(s, a, Wsa_t, bsa, Wse_t, bse, Wp_t, bv,
                                                   mst_g, flag, SEb, SEL, KEY, VAL);
  k_attn2<<<BATCH / 8, 256, 0, stream>>>(SEL, KEY, VAL);
  k_critic<<<dim3(BATCH / 128, NA), 256, 0, stream>>>(SEb, SEL, a, Wc1t, bc1, Wc2, bc2, flag, d_out);
}

// Round 7
// 247.774 us; speedup vs baseline: 1.1863x; 1.0599x over previous
//
#include <hip/hip_runtime.h>

// Attention_Critic on MI355X — round 16: resubmit of round 15 (infra failure, no data).
//  - k_critic2: N-split GEMM (B read once/block, was 4x), amax hoisted to top
//    with coalesced 16B loads + shfl combine, wc2f staging hoisted (latency
//    hides under GEMM staging), gather vectorized (8x lds_s8 instead of 64
//    scalar conflicted u16 reads). Same f32 dot + first-max semantics.
//  - k_attn2: depth-1 software pipeline on SEL/KEY fragment loads (head 0
//    before VAL staging; head p+1 prefetched before head p's softmax chain).
//  - k_prep2 / k_fin / k_enc7: byte-identical to round 14.
//
// ws layout (bytes):
//   [0,256)          int flag (1 = bf16 inputs, 0 = f32)
//   [1024,+1310720)  stats partials f32 [8][256][160]
//   [1311744,+5120)  mst_g f32 [8][80][2]
//   [1316864,...)    Wsa_t bf16 [8][128 col][104 k]
//   [1529856,...)    Wse_t bf16 [8][128 col][72 k]
//   [1677312,...)    Wp_t  bf16 [3 mat][128 col][136 k]  (mat 0=sel,1=key,2=val)
//   [1781760,...)    Wc1t  bf16 [8][128 col][256 k]
//   [2306048,+32M)   SE   bf16 [8][16384][128]           (agent-major)
//   [+32M,+64M)      SEL2 bf16 [16384*8][128] row=b*8+agent (attn writes OT in place)
//   [+64M,+96M)      KEY2 bf16 [16384*8][128] row=b*8+agent
//   [+96M,+128M)     VAL2 bf16 [16384*8][128] row=b*8+agent

typedef unsigned short u16;
typedef unsigned int u32;

#define NA 8
#define BATCH 16384
#define SD 64
#define AD 16
#define IND 80
#define HID 128
#define HEADS 4
#define ATT 32
#define EPS 1e-5f
#define KP 136    // u16 stride, 128-k tiles (16B-aligned rows)
#define KP3 104   // u16 stride, 96-k tiles (Wsa_t)
#define KPS 72    // u16 stride, 64-k tiles (Wse_t)
#define VTS 68    // u16 stride, valt [32 d][64 row']
#define WBS 24    // u16 stride, softmax weight tiles

using short8 = __attribute__((ext_vector_type(8))) short;
using float4f = __attribute__((ext_vector_type(4))) float;
using uint4v = __attribute__((ext_vector_type(4))) u32;
#define MFMA16(a, b, c) __builtin_amdgcn_mfma_f32_16x16x32_bf16((a), (b), (c), 0, 0, 0)

__device__ __forceinline__ float bf2f(u16 u) { union { u32 i; float f; } v; v.i = ((u32)u) << 16; return v.f; }
__device__ __forceinline__ float lo2f(u32 w) { union { u32 i; float f; } v; v.i = w << 16; return v.f; }
__device__ __forceinline__ float hi2f(u32 w) { union { u32 i; float f; } v; v.i = w & 0xffff0000u; return v.f; }
__device__ __forceinline__ u16 f2bf(float f) {
  union { float f; u32 i; } v; v.f = f;
  u32 x = v.i;
  x += 0x7fffu + ((x >> 16) & 1u);   // RNE
  return (u16)(x >> 16);
}
__device__ __forceinline__ float lrelu(float x) { return x > 0.f ? x : 0.01f * x; }
__device__ __forceinline__ float ldin(const void* p, size_t i, bool bf) {
  return bf ? bf2f(((const u16*)p)[i]) : ((const float*)p)[i];
}
__device__ __forceinline__ u16 ldbf(const void* p, size_t i, bool bf) {
  return bf ? ((const u16*)p)[i] : f2bf(((const float*)p)[i]);
}
__device__ __forceinline__ short8 lds_s8(const u16* p) {   // 16B LDS load, 4B-aligned ok
  union { short8 v; u32 u[4]; } t;
  const u32* q = (const u32*)p;
  t.u[0] = q[0]; t.u[1] = q[1]; t.u[2] = q[2]; t.u[3] = q[3];
  return t.v;
}
// Barrier that orders LDS only: global stores stay in flight.
__device__ __forceinline__ void barlg() {
  asm volatile("s_waitcnt lgkmcnt(0)" ::: "memory");
  __builtin_amdgcn_s_barrier();
}

// ---------------- K1: merged BN stats (2048 blocks) + weight prep (60 blocks) ----------------
__global__ __launch_bounds__(256) void k_prep2(
    const void* __restrict__ s, const void* __restrict__ a,
    const void* __restrict__ Wsa, const void* __restrict__ Wse,
    const void* __restrict__ Wsl, const void* __restrict__ Wk, const void* __restrict__ Wv,
    const void* __restrict__ Wc1,
    int* __restrict__ flag, float* __restrict__ part,
    u16* __restrict__ Wsa_t, u16* __restrict__ Wse_t, u16* __restrict__ Wp_t, u16* __restrict__ Wc1t) {
  __shared__ u16 T[80 * 130];
  __shared__ float S0[256], Q0[256], S1[256], Q1[256];
  __shared__ int cnt[2];
  int tid = threadIdx.x;
  if (tid < 2) cnt[tid] = 0;
  __syncthreads();
  {   // local dtype detection (all blocks, first 1KB of s)
    u32 wv = ((const u32*)s)[tid];
    u32 lo = wv & 0xffffu, e = (lo >> 7) & 0xffu;
    if (lo == 0u || lo == 0x8000u) atomicAdd(&cnt[1], 1);
    else if (e < 0x70u || e > 0x8fu) atomicAdd(&cnt[0], 1);
  }
  __syncthreads();
  bool bf = !(cnt[0] >= 64 || cnt[1] >= 192);
  if (blockIdx.x == 0 && tid == 0) *flag = bf ? 1 : 0;
  int blkr = blockIdx.x;
  if (blkr < 2048) {   // ---- stats chunk: 64 rows ----
    int n = blkr >> 8, c = blkr & 255, b0 = c << 6;
    float* p = part + (size_t)(n * 256 + c) * 160;
    {
      int f2 = tid & 31, rg = tid >> 5;          // 8 row-groups
      float s0 = 0.f, s1 = 0.f, q0 = 0.f, q1 = 0.f;
      #pragma unroll
      for (int i = 0; i < 8; i++) {
        int b = b0 + rg + 8 * i;
        float x0, x1;
        if (bf) { u32 wv = ((const u32*)s)[((size_t)n * BATCH + b) * 32 + f2]; x0 = lo2f(wv); x1 = hi2f(wv); }
        else { const float* sf = (const float*)s + ((size_t)n * BATCH + b) * 64 + 2 * f2; x0 = sf[0]; x1 = sf[1]; }
        s0 += x0; q0 += x0 * x0; s1 += x1; q1 += x1 * x1;
      }
      S0[tid] = s0; Q0[tid] = q0; S1[tid] = s1; Q1[tid] = q1;
    }
    __syncthreads();
    if (tid < 64) {
      int f2 = tid >> 1, odd = tid & 1;
      float S = 0.f, Q = 0.f;
      #pragma unroll
      for (int rg = 0; rg < 8; rg++) {
        int ix = rg * 32 + f2;
        S += odd ? S1[ix] : S0[ix];
        Q += odd ? Q1[ix] : Q0[ix];
      }
      p[tid * 2] = S; p[tid * 2 + 1] = Q;
    }
    __syncthreads();
    {
      int f2 = tid & 7, rg = tid >> 3;           // 32 row-groups
      float s0 = 0.f, s1 = 0.f, q0 = 0.f, q1 = 0.f;
      #pragma unroll
      for (int i = 0; i < 2; i++) {
        int b = b0 + rg + 32 * i;
        float x0, x1;
        if (bf) { u32 wv = ((const u32*)a)[((size_t)n * BATCH + b) * 8 + f2]; x0 = lo2f(wv); x1 = hi2f(wv); }
        else { const float* af = (const float*)a + ((size_t)n * BATCH + b) * 16 + 2 * f2; x0 = af[0]; x1 = af[1]; }
        s0 += x0; q0 += x0 * x0; s1 += x1; q1 += x1 * x1;
      }
      S0[tid] = s0; Q0[tid] = q0; S1[tid] = s1; Q1[tid] = q1;
    }
    __syncthreads();
    if (tid < 16) {
      int f2 = tid >> 1, odd = tid & 1;
      float S = 0.f, Q = 0.f;
      #pragma unroll
      for (int rg = 0; rg < 32; rg++) {
        int ix = rg * 8 + f2;
        S += odd ? S1[ix] : S0[ix];
        Q += odd ? Q1[ix] : Q0[ix];
      }
      p[(SD + tid) * 2] = S; p[(SD + tid) * 2 + 1] = Q;
    }
    return;
  }
  int blk = blkr - 2048;   // ---- weight prep ----
  if (blk < 32) {                       // Wc1 [n][256][128] -> Wc1t [n][128][256]
    int n = blk >> 2, k0 = (blk & 3) * 64;
    for (int i = tid; i < 64 * 128; i += 256) {
      int kr = i >> 7, cc = i & 127;
      T[kr * 130 + cc] = ldbf(Wc1, ((size_t)n * 256 + k0 + kr) * 128 + cc, bf);
    }
    __syncthreads();
    for (int i = tid; i < 128 * 64; i += 256) {
      int col = i >> 6, kk = i & 63;
      Wc1t[((size_t)n * 128 + col) * 256 + k0 + kk] = T[kk * 130 + col];
    }
  } else if (blk < 40) {                // Wsa -> Wsa_t
    int n = blk - 32;
    for (int i = tid; i < 80 * 128; i += 256) {
      int kr = i >> 7, cc = i & 127;
      T[kr * 130 + cc] = ldbf(Wsa, ((size_t)n * IND + kr) * 128 + cc, bf);
    }
    __syncthreads();
    for (int i = tid; i < 128 * KP3; i += 256) {
      int col = i / KP3, k = i - col * KP3;
      Wsa_t[((size_t)n * 128 + col) * KP3 + k] = (k < IND) ? T[k * 130 + col] : (u16)0;
    }
  } else if (blk < 48) {                // Wse -> Wse_t
    int n = blk - 40;
    for (int i = tid; i < 64 * 128; i += 256) {
      int kr = i >> 7, cc = i & 127;
      T[kr * 130 + cc] = ldbf(Wse, ((size_t)n * SD + kr) * 128 + cc, bf);
    }
    __syncthreads();
    for (int i = tid; i < 128 * KPS; i += 256) {
      int col = i / KPS, k = i - col * KPS;
      Wse_t[((size_t)n * 128 + col) * KPS + k] = (k < SD) ? T[k * 130 + col] : (u16)0;
    }
  } else {                              // Wp -> Wp_t [mat][col=p*32+d][KP]
    int pm = blk - 48, p = pm / 3, mat = pm - 3 * p;
    const void* W = (mat == 0) ? Wsl : (mat == 1) ? Wk : Wv;
    for (int i = tid; i < 128 * 32; i += 256) {
      int kr = i >> 5, d = i & 31;
      T[kr * 34 + d] = ldbf(W, ((size_t)p * HID + kr) * ATT + d, bf);
    }
    __syncthreads();
    for (int i = tid; i < 32 * KP; i += 256) {
      int d = i / KP, k = i - d * KP;
      Wp_t[((size_t)mat * HID + p * ATT + d) * KP + k] = (k < HID) ? T[k * 34 + d] : (u16)0;
    }
  }
}

// ---------------- K1b: fold stats partials (coalesced) -> mst_g[8][80][2] ----------------
__global__ __launch_bounds__(256) void k_fin(const float* __restrict__ part, float* __restrict__ mst_g) {
  int n = blockIdx.x;
  int t = threadIdx.x;
  if (t < 160) {
    const float* p = part + (size_t)n * 256 * 160 + t;
    float acc = 0.f;
    #pragma unroll 8
    for (int c = 0; c < 256; c++) acc += p[(size_t)c * 160];
    float other = __shfl_xor(acc, 1);
    if ((t & 1) == 0) {
      float mean = acc * (1.f / BATCH);
      float var = other * (1.f / BATCH) - mean * mean;
      mst_g[(size_t)n * 160 + t] = mean;
      mst_g[(size_t)n * 160 + t + 1] = rsqrtf(var + EPS);
    }
  }
}

// ---------------- K2: sequential-phase encoders + N-split projections ----------------
// (byte-identical to round 14)
__global__ __launch_bounds__(256) void k_enc7(
    const void* __restrict__ s, const void* __restrict__ a,
    const u16* __restrict__ Wsa_t, const void* __restrict__ bsa,
    const u16* __restrict__ Wse_t, const void* __restrict__ bse,
    const u16* __restrict__ Wp_t, const void* __restrict__ bv_g,
    const float* __restrict__ mst_g, const int* __restrict__ flag,
    u16* __restrict__ SEo, u16* __restrict__ SEL2, u16* __restrict__ KEY2, u16* __restrict__ VAL2) {
  __shared__ __align__(16) u16 A[64 * KP];    // sanb (cols 0..95) -> E (cols 0..127)
  __shared__ __align__(16) u16 Bt[64 * KP];   // SE
  __shared__ float mst[IND * 2];
  __shared__ float bsaf[HID], bsef[HID], bvf[HID];
  bool bf = (*flag != 0);
  int tid = threadIdx.x;
  int n = blockIdx.y;
  int b0 = blockIdx.x * 64;
  int w = tid >> 6, lane = tid & 63, q = lane >> 4, rl = lane & 15;
  if (tid < HID) {
    bsaf[tid] = ldin(bsa, n * HID + tid, bf);
    bsef[tid] = ldin(bse, n * HID + tid, bf);
    bvf[tid]  = ldin(bv_g, tid, bf);
  }
  if (tid < IND * 2) mst[tid] = mst_g[(size_t)n * IND * 2 + tid];
  barlg();   // B0
  for (int i = tid; i < 64 * 32; i += 256) {          // s-part k 0..63
    int row = i >> 5, kp = i & 31;
    float x0, x1;
    if (bf) { u32 wv = ((const u32*)s)[((size_t)n * BATCH + b0 + row) * 32 + kp]; x0 = lo2f(wv); x1 = hi2f(wv); }
    else { const float* sf = (const float*)s + ((size_t)n * BATCH + b0 + row) * 64 + 2 * kp; x0 = sf[0]; x1 = sf[1]; }
    int k = 2 * kp;
    u32 o = (u32)f2bf((x0 - mst[k * 2]) * mst[k * 2 + 1]) |
            ((u32)f2bf((x1 - mst[k * 2 + 2]) * mst[k * 2 + 3]) << 16);
    *(u32*)&A[row * KP + k] = o;
  }
  for (int i = tid; i < 64 * 8; i += 256) {           // a-part k 64..79
    int row = i >> 3, kp = i & 7;
    float x0, x1;
    if (bf) { u32 wv = ((const u32*)a)[((size_t)n * BATCH + b0 + row) * 8 + kp]; x0 = lo2f(wv); x1 = hi2f(wv); }
    else { const float* af = (const float*)a + ((size_t)n * BATCH + b0 + row) * 16 + 2 * kp; x0 = af[0]; x1 = af[1]; }
    int k = SD + 2 * kp;
    u32 o = (u32)f2bf((x0 - mst[k * 2]) * mst[k * 2 + 1]) |
            ((u32)f2bf((x1 - mst[k * 2 + 2]) * mst[k * 2 + 3]) << 16);
    *(u32*)&A[row * KP + k] = o;
  }
  for (int i = tid; i < 64 * 8; i += 256) {           // zero pad k 80..95
    int row = i >> 3, c2 = i & 7;
    *(u32*)&A[row * KP + IND + 2 * c2] = 0u;
  }
  barlg();   // B1: sanb staged
  const u16* WS = Wse_t + (size_t)n * HID * KPS;
  const u16* WA = Wsa_t + (size_t)n * HID * KP3;
  // ---- phase 1: SE acc (K=64); retire immediately ----
  {
    float4f accS[8] = {};
    #pragma unroll
    for (int kc = 0; kc < 2; kc++) {
      short8 a0 = *(const short8*)&A[(w * 16 + rl) * KP + kc * 32 + q * 8];
      #pragma unroll
      for (int nt = 0; nt < 8; nt++) {
        short8 bb = *(const short8*)(WS + (size_t)(nt * 16 + rl) * KPS + kc * 32 + q * 8);
        accS[nt] = MFMA16(a0, bb, accS[nt]);
      }
    }
    #pragma unroll
    for (int nt = 0; nt < 8; nt++)
      #pragma unroll
      for (int r = 0; r < 4; r++) {
        int row = w * 16 + q * 4 + r, col = nt * 16 + rl;
        u16 v = f2bf(lrelu(accS[nt][r] + bsef[col]));
        SEo[((size_t)n * BATCH + b0 + row) * HID + col] = v;
        Bt[row * KP + col] = v;                        // wave-private rows
      }
  }
  __builtin_amdgcn_sched_barrier(0);
  // ---- phase 2: E acc (K=96) ----
  {
    float4f accE[8] = {};
    #pragma unroll
    for (int kc = 0; kc < 3; kc++) {
      short8 a0 = *(const short8*)&A[(w * 16 + rl) * KP + kc * 32 + q * 8];
      #pragma unroll
      for (int nt = 0; nt < 8; nt++) {
        short8 bb = *(const short8*)(WA + (size_t)(nt * 16 + rl) * KP3 + kc * 32 + q * 8);
        accE[nt] = MFMA16(a0, bb, accE[nt]);
      }
    }
    barlg();   // B2: ALL sanb reads done
    #pragma unroll
    for (int nt = 0; nt < 8; nt++)
      #pragma unroll
      for (int r = 0; r < 4; r++) {
        int row = w * 16 + q * 4 + r, col = nt * 16 + rl;
        A[row * KP + col] = f2bf(lrelu(accE[nt][r] + bsaf[col]));   // E over sanb
      }
  }
  barlg();   // B3: E (A) and SE (Bt) tiles fully visible
  const u16* WSL = Wp_t;                               // mat 0, [128][KP]
  const u16* WKm = Wp_t + (size_t)HID * KP;            // mat 1
  const u16* WVm = Wp_t + (size_t)2 * HID * KP;        // mat 2
  // ---- phase 3: KEY = E @ Wk (N-split) ----
  {
    float4f ac[4][2] = {};
    #pragma unroll
    for (int kc = 0; kc < 4; kc++) {
      short8 af[4];
      #pragma unroll
      for (int mt = 0; mt < 4; mt++)
        af[mt] = *(const short8*)&A[(mt * 16 + rl) * KP + kc * 32 + q * 8];
      #pragma unroll
      for (int nt = 0; nt < 2; nt++) {
        short8 bk = *(const short8*)(WKm + (size_t)(w * 32 + nt * 16 + rl) * KP + kc * 32 + q * 8);
        #pragma unroll
        for (int mt = 0; mt < 4; mt++)
          ac[mt][nt] = MFMA16(af[mt], bk, ac[mt][nt]);
      }
    }
    #pragma unroll
    for (int mt = 0; mt < 4; mt++)
      #pragma unroll
      for (int nt = 0; nt < 2; nt++)
        #pragma unroll
        for (int r = 0; r < 4; r++) {
          int row = mt * 16 + q * 4 + r, col = w * 32 + nt * 16 + rl;
          KEY2[((size_t)(b0 + row) * NA + n) * HID + col] = f2bf(ac[mt][nt][r]);
        }
  }
  __builtin_amdgcn_sched_barrier(0);
  // ---- phase 4: VAL = lrelu(E @ Wv + bv) (N-split) ----
  {
    float4f ac[4][2] = {};
    #pragma unroll
    for (int kc = 0; kc < 4; kc++) {
      short8 af[4];
      #pragma unroll
      for (int mt = 0; mt < 4; mt++)
        af[mt] = *(const short8*)&A[(mt * 16 + rl) * KP + kc * 32 + q * 8];
      #pragma unroll
      for (int nt = 0; nt < 2; nt++) {
        short8 bv8 = *(const short8*)(WVm + (size_t)(w * 32 + nt * 16 + rl) * KP + kc * 32 + q * 8);
        #pragma unroll
        for (int mt = 0; mt < 4; mt++)
          ac[mt][nt] = MFMA16(af[mt], bv8, ac[mt][nt]);
      }
    }
    #pragma unroll
    for (int mt = 0; mt < 4; mt++)
      #pragma unroll
      for (int nt = 0; nt < 2; nt++)
        #pragma unroll
        for (int r = 0; r < 4; r++) {
          int row = mt * 16 + q * 4 + r, col = w * 32 + nt * 16 + rl;
          VAL2[((size_t)(b0 + row) * NA + n) * HID + col] = f2bf(lrelu(ac[mt][nt][r] + bvf[col]));
        }
  }
  __builtin_amdgcn_sched_barrier(0);
  // ---- phase 5: SEL = SE @ Wsel (N-split from Bt) ----
  {
    float4f ac[4][2] = {};
    #pragma unroll
    for (int kc = 0; kc < 4; kc++) {
      short8 af[4];
      #pragma unroll
      for (int mt = 0; mt < 4; mt++)
        af[mt] = *(const short8*)&Bt[(mt * 16 + rl) * KP + kc * 32 + q * 8];
      #pragma unroll
      for (int nt = 0; nt < 2; nt++) {
        short8 bl = *(const short8*)(WSL + (size_t)(w * 32 + nt * 16 + rl) * KP + kc * 32 + q * 8);
        #pragma unroll
        for (int mt = 0; mt < 4; mt++)
          ac[mt][nt] = MFMA16(af[mt], bl, ac[mt][nt]);
      }
    }
    #pragma unroll
    for (int mt = 0; mt < 4; mt++)
      #pragma unroll
      for (int nt = 0; nt < 2; nt++)
        #pragma unroll
        for (int r = 0; r < 4; r++) {
          int row = mt * 16 + q * 4 + r, col = w * 32 + nt * 16 + rl;
          SEL2[((size_t)(b0 + row) * NA + n) * HID + col] = f2bf(ac[mt][nt][r]);
        }
  }
}

// ---------------- K3: attention, depth-1 fragment prefetch ----------------
// LDS: valt 17408 + wb 3072 = 20480 B.
// SELO not __restrict__: head-p reads precede head-p writes (wave-private rows).
__global__ __launch_bounds__(256) void k_attn2(
    u16* SELO, const u16* __restrict__ KEY, const u16* __restrict__ VAL) {
  __shared__ __align__(16) u16 valt[HEADS * ATT * VTS];   // [p*32+d][row'=b*8+j]
  __shared__ u16 wb[64 * WBS];                            // softmax weights, wave-private rows
  int tid = threadIdx.x;
  size_t r0 = (size_t)blockIdx.x * 64;                    // 8 batches x 8 agents
  int w = tid >> 6, lane = tid & 63, q = lane >> 4, rl = lane & 15;
  // head-0 fragment loads issued FIRST (fully hidden under staging + barrier)
  const size_t fbase = (r0 + w * 16 + rl) * HID;
  short8 sa = *(const short8*)(SELO + fbase + q * 8);
  short8 kb = *(const short8*)(KEY + fbase + q * 8);
  // stage VAL -> valt (transposed; source fully coalesced)
  {
    const u32* vu = (const u32*)VAL;
    #pragma unroll
    for (int t = 0; t < 16; t++) {
      int idx = tid + t * 256;
      int rp = idx >> 6, c2 = idx & 63;   // rp = b*8 + agent
      u32 wv = vu[(r0 + rp) * 64 + c2];
      int c = 2 * c2;
      valt[c * VTS + rp] = (u16)(wv & 0xffffu);
      valt[(c + 1) * VTS + rp] = (u16)(wv >> 16);
    }
  }
  barlg();   // the only barrier
  const float scale = 0.17677669529663687f;
  #pragma unroll
  for (int p = 0; p < HEADS; p++) {
    // prefetch next head's fragments before this head's softmax chain
    short8 nsa = sa, nkb = kb;
    if (p < HEADS - 1) {
      nsa = *(const short8*)(SELO + fbase + (p + 1) * ATT + q * 8);
      nkb = *(const short8*)(KEY + fbase + (p + 1) * ATT + q * 8);
    }
    float4f zc = {};
    float4f c = MFMA16(sa, kb, zc);
    int nn = rl;
    #pragma unroll
    for (int r = 0; r < 4; r++) {
      int row = q * 4 + r;
      float x = c[r] * scale;
      if (row == nn) x = -1e9f;                    // self-mask (same b, i==j)
      float mx = x;
      mx = fmaxf(mx, __shfl_xor(mx, 1));
      mx = fmaxf(mx, __shfl_xor(mx, 2));
      mx = fmaxf(mx, __shfl_xor(mx, 4));
      float e = __expf(x - mx);
      float ssum = e;
      ssum += __shfl_xor(ssum, 1);
      ssum += __shfl_xor(ssum, 2);
      ssum += __shfl_xor(ssum, 4);
      float wv = e / ssum;
      if ((row >> 3) != (nn >> 3)) wv = 0.f;       // zero cross-b junk
      wb[(w * 16 + row) * WBS + nn] = f2bf(wv);    // wave-private rows
    }
    short8 aw;
    if (q < 2) aw = *(const short8*)&wb[(w * 16 + rl) * WBS + q * 8];
    else { short8 z = {}; aw = z; }
    float4f o[2] = {};
    #pragma unroll
    for (int nt = 0; nt < 2; nt++) {
      short8 bv8 = lds_s8(&valt[(p * ATT + nt * 16 + rl) * VTS + w * 16 + (q & 1) * 8]);
      o[nt] = MFMA16(aw, bv8, o[nt]);
    }
    #pragma unroll
    for (int nt = 0; nt < 2; nt++)
      #pragma unroll
      for (int r = 0; r < 4; r++) {
        int row = q * 4 + r;
        int rp = w * 16 + (row >> 3) * 8 + (row & 7);   // b*8 + agent
        SELO[(r0 + rp) * HID + p * ATT + nt * 16 + rl] = f2bf(o[nt][r]);
      }
    sa = nsa; kb = nkb;
  }
}

// ---------------- K4: critic — N-split GEMM, hoisted amax/wc2f, vector gather ----------------
// LDS: Xt 34816 + wc2f 8192 + bc1f 512 + amax 512 = 44032 B
__global__ __launch_bounds__(256) void k_critic2(
    const u16* __restrict__ SEi, const u16* __restrict__ OT, const void* __restrict__ a_g,
    const u16* __restrict__ Wc1t, const void* __restrict__ bc1_g,
    const void* __restrict__ Wc2_g, const void* __restrict__ bc2_g,
    const int* __restrict__ flag, void* __restrict__ qo) {
  __shared__ __align__(16) u16 Xt[128 * KP];   // input rows; reused as ht
  __shared__ float wc2f[HID * AD];
  __shared__ float bc1f[HID];
  __shared__ int amax[128];
  bool bf = (*flag != 0);
  int tid = threadIdx.x;
  int n = blockIdx.y;
  int b0 = blockIdx.x * 128;
  int w = tid >> 6, lane = tid & 63, q = lane >> 4, rl = lane & 15;
  if (tid < HID) bc1f[tid] = ldin(bc1_g, n * HID + tid, bf);
  // ---- amax hoisted to top: coalesced 16/32B loads + shfl combine ----
  {
    int b = tid >> 1, half = tid & 1;
    float best; int bi;
    if (bf) {
      const uint4v* pa = (const uint4v*)((const u32*)a_g + ((size_t)n * BATCH + b0 + b) * 8 + half * 4);
      uint4v x = *pa;
      float v[8] = {lo2f(x[0]), hi2f(x[0]), lo2f(x[1]), hi2f(x[1]),
                    lo2f(x[2]), hi2f(x[2]), lo2f(x[3]), hi2f(x[3])};
      best = v[0]; bi = 0;
      #pragma unroll
      for (int j = 1; j < 8; j++) if (v[j] > best) { best = v[j]; bi = j; }
    } else {
      const float* pa = (const float*)a_g + ((size_t)n * BATCH + b0 + b) * 16 + half * 8;
      float4f v0 = *(const float4f*)pa, v1 = *(const float4f*)(pa + 4);
      float v[8] = {v0[0], v0[1], v0[2], v0[3], v1[0], v1[1], v1[2], v1[3]};
      best = v[0]; bi = 0;
      #pragma unroll
      for (int j = 1; j < 8; j++) if (v[j] > best) { best = v[j]; bi = j; }
    }
    float ob = __shfl_xor(best, 1);
    int obi = __shfl_xor(bi, 1);
    if (half == 0) amax[b] = (ob > best) ? (obi + 8) : bi;   // strict > = first-max
  }
  // ---- wc2f staging hoisted (latency hides under GEMM staging) ----
  for (int idx = tid; idx < HID * AD; idx += 256)
    wc2f[idx] = ldin(Wc2_g, (size_t)n * HID * AD + idx, bf);
  const u16* WT = Wc1t + (size_t)n * HID * 256;

  // ---- K=256 GEMM, N-split (wave owns 32 cols; B read once per block) ----
  float4f acc[8][2] = {};
  for (int ph = 0; ph < 2; ph++) {
    for (int idx = tid; idx < 128 * 64; idx += 256) {
      int row = idx >> 6, c = idx & 63;
      u32 wv;
      if (ph == 0) wv = ((const u32*)SEi)[((size_t)n * BATCH + b0 + row) * 64 + c];
      else         wv = ((const u32*)OT)[((size_t)(b0 + row) * NA + n) * 64 + c];
      ((u32*)&Xt[row * KP])[c] = wv;
    }
    barlg();
    #pragma unroll
    for (int kc = 0; kc < 4; kc++) {
      int ko = ph * HID + kc * 32;
      short8 bb0 = *(const short8*)(WT + (size_t)(w * 32 + rl) * 256 + ko + q * 8);
      short8 bb1 = *(const short8*)(WT + (size_t)(w * 32 + 16 + rl) * 256 + ko + q * 8);
      #pragma unroll
      for (int mt = 0; mt < 8; mt++) {
        short8 af = *(const short8*)&Xt[(mt * 16 + rl) * KP + kc * 32 + q * 8];
        acc[mt][0] = MFMA16(af, bb0, acc[mt][0]);
        acc[mt][1] = MFMA16(af, bb1, acc[mt][1]);
      }
    }
    barlg();
  }
  u16* ht = Xt;
  #pragma unroll
  for (int mt = 0; mt < 8; mt++)
    #pragma unroll
    for (int nt = 0; nt < 2; nt++)
      #pragma unroll
      for (int r = 0; r < 4; r++) {
        int row = mt * 16 + q * 4 + r, col = w * 32 + nt * 16 + rl;
        ht[row * KP + col] = f2bf(lrelu(acc[mt][nt][r] + bc1f[col]));
      }
  barlg();
  {
    int b = tid >> 1, half = tid & 1;
    int col = amax[b];
    float acq = 0.f;
    const u16* hr = &ht[b * KP + half * 64];
    const float* wz = &wc2f[(half * 64) * AD + col];
    #pragma unroll
    for (int kk = 0; kk < 8; kk++) {
      short8 hv = lds_s8(hr + kk * 8);
      #pragma unroll
      for (int j = 0; j < 8; j++)
        acq = fmaf(bf2f((u16)hv[j]), wz[(kk * 8 + j) * AD], acq);
    }
    acq += __shfl_xor(acq, 1);
    if (half == 0) {
      float v = acq + ldin(bc2_g, n * AD + col, bf);
      size_t oidx = (size_t)n * BATCH + b0 + b;
      if (bf) ((u16*)qo)[oidx] = f2bf(v);
      else    ((float*)qo)[oidx] = v;
    }
  }
}

extern "C" void kernel_launch(void* const* d_in, const int* in_sizes, int n_in,
                              void* d_out, int out_size, void* d_ws, size_t ws_size,
                              hipStream_t stream) {
  const void* s   = d_in[0];
  const void* a   = d_in[1];
  const void* Wsa = d_in[2];
  const void* bsa = d_in[3];
  const void* Wse = d_in[4];
  const void* bse = d_in[5];
  const void* Wk  = d_in[6];
  const void* Wsl = d_in[7];
  const void* Wv  = d_in[8];
  const void* bv  = d_in[9];
  const void* Wc1 = d_in[10];
  const void* bc1 = d_in[11];
  const void* Wc2 = d_in[12];
  const void* bc2 = d_in[13];

  char* ws = (char*)d_ws;
  int*   flag  = (int*)ws;
  float* part  = (float*)(ws + 1024);
  float* mst_g = (float*)(ws + 1311744);
  u16*   Wsa_t = (u16*)(ws + 1316864);
  u16*   Wse_t = (u16*)(ws + 1529856);
  u16*   Wp_t  = (u16*)(ws + 1677312);
  u16*   Wc1t  = (u16*)(ws + 1781760);
  u16*   SEb   = (u16*)(ws + 2306048);
  u16*   SEL   = (u16*)(ws + 2306048 + 1ull * 33554432ull);
  u16*   KEY   = (u16*)(ws + 2306048 + 2ull * 33554432ull);
  u16*   VAL   = (u16*)(ws + 2306048 + 3ull * 33554432ull);

  k_prep2<<<2108, 256, 0, stream>>>(s, a, Wsa, Wse, Wsl, Wk, Wv, Wc1,
                                    flag, part, Wsa_t, Wse_t, Wp_t, Wc1t);
  k_fin<<<NA, 256, 0, stream>>>(part, mst_g);
  k_enc7<<<dim3(BATCH / 64, NA), 256, 0, stream>>>(s, a, Wsa_t, bsa, Wse_t, bse, Wp_t, bv,
                                                   mst_g, flag, SEb, SEL, KEY, VAL);
  k_attn2<<<BATCH / 8, 256, 0, stream>>>(SEL, KEY, VAL);
  k_critic2<<<dim3(BATCH / 128, NA), 256, 0, stream>>>(SEb, SEL, a, Wc1t, bc1, Wc2, bc2, flag, d_out);
}